// Round 3
// baseline (152.091 us; speedup 1.0000x reference)
//
#include <hip/hip_runtime.h>
#include <math.h>

#define B_    32
#define L_    16384
#define C_    128
#define KTOP  64
#define NCOL  (B_ * C_)      // 4096 columns
#define CAPMAX 512           // per-column candidate capacity (8 regs/lane * 64)
#define T0    2.25f          // filter threshold; E[count>T0] ~ 200/column, sd ~14
                             // P(count < 64) ~ 1e-21 per column

// lexicographic (value, index) less-than
__device__ __forceinline__ bool lex_lt(float v1, int i1, float v2, int i2) {
    return (v1 < v2) || ((v1 == v2) && (i1 < i2));
}

__device__ __forceinline__ void push_cand(int col, int l, float v,
                                          int* __restrict__ cnt,
                                          float* __restrict__ cval,
                                          int* __restrict__ cidx, int cap) {
    int p = atomicAdd(&cnt[col], 1);
    if (p < cap) {
        size_t o = (size_t)col * cap + p;
        cval[o] = v;
        cidx[o] = l;
    }
}

// Zero the per-column candidate counters (hipMemsetAsync was slow in-graph).
__global__ __launch_bounds__(256) void k_zero(int* __restrict__ cnt) {
    cnt[blockIdx.x * 256 + threadIdx.x] = 0;
}

// Pass 1: stream all of x (coalesced float4), compact values > T0 per column.
// grid: (L_/256, B_), block: 256 threads (8 rows x 32 float4-lanes)
__global__ __launch_bounds__(256) void k_filter(const float* __restrict__ x,
                                                int* __restrict__ cnt,
                                                float* __restrict__ cval,
                                                int* __restrict__ cidx,
                                                int cap) {
    const int b  = blockIdx.y;
    const int l0 = blockIdx.x * 256;
    const int r  = threadIdx.x >> 5;     // 0..7 row within group
    const int c4 = threadIdx.x & 31;     // float4 slot within row (0..31)
    const float4* xb = (const float4*)x + (size_t)b * L_ * (C_ / 4);
    const int cbase = b * C_ + c4 * 4;

    for (int l = l0 + r; l < l0 + 256; l += 8) {
        float4 v = xb[(size_t)l * (C_ / 4) + c4];
        // early-out: skip the push branches when no lane in the wave has any
        // candidate in this iteration (~46% of iterations at T0=2.25)
        float m = fmaxf(fmaxf(v.x, v.y), fmaxf(v.z, v.w));
        if (__any(m > T0)) {
            if (v.x > T0) push_cand(cbase + 0, l, v.x, cnt, cval, cidx, cap);
            if (v.y > T0) push_cand(cbase + 1, l, v.y, cnt, cval, cidx, cap);
            if (v.z > T0) push_cand(cbase + 2, l, v.z, cnt, cval, cidx, cap);
            if (v.w > T0) push_cand(cbase + 3, l, v.w, cnt, cval, cidx, cap);
        }
    }
}

// Pass 2: ONE WAVE per column (4 columns per 256-block). Register tournament:
// 64 rounds of {local max over 8 regs -> shfl_xor butterfly -> clear winner}.
// No LDS, no barriers. Temporal order restored by ranking winner indices.
// Fallback (count < KTOP or buffer overflow): exact lexicographic descent.
__global__ __launch_bounds__(256) void k_select(const float* __restrict__ x,
                                                const int* __restrict__ cnt,
                                                const float* __restrict__ cval,
                                                const int* __restrict__ cidx,
                                                float* __restrict__ out,
                                                int cap) {
    const int wave = threadIdx.x >> 6;           // 0..3
    const int lane = threadIdx.x & 63;
    const int col  = blockIdx.x * 4 + wave;
    const int b    = col >> 7;
    const int c    = col & (C_ - 1);

    const int n = (cap > 0) ? cnt[col] : 0;

    float keepv = 0.0f;
    int   keepi = 0;

    if (n >= KTOP && n <= cap) {
        // ---- fast path: load candidates into registers (8 slots/lane) ----
        float v[8];
        int   idx[8];
#pragma unroll
        for (int s = 0; s < 8; ++s) {
            int p = lane + s * 64;
            bool ok = (p < n);
            size_t o = (size_t)col * cap + p;
            v[s]   = ok ? cval[o] : -INFINITY;
            idx[s] = ok ? cidx[o] : -1;
        }
        for (int k = 0; k < KTOP; ++k) {
            // local best among 8 regs
            float bv = v[0];
            int   bi = idx[0];
#pragma unroll
            for (int s = 1; s < 8; ++s)
                if (lex_lt(bv, bi, v[s], idx[s])) { bv = v[s]; bi = idx[s]; }
            // wave butterfly reduce (lex max)
#pragma unroll
            for (int off = 32; off; off >>= 1) {
                float ov = __shfl_xor(bv, off, 64);
                int   oi = __shfl_xor(bi, off, 64);
                if (lex_lt(bv, bi, ov, oi)) { bv = ov; bi = oi; }
            }
            if (lane == k) { keepv = bv; keepi = bi; }
            // clear winner (indices are unique within a column; bi >= 0 always
            // since n >= KTOP real candidates exist)
#pragma unroll
            for (int s = 0; s < 8; ++s)
                if (idx[s] == bi) { v[s] = -INFINITY; idx[s] = -1; }
        }
    } else {
        // ---- exact fallback: lexicographic-descent argmax, 64 rounds ----
        const float* xc = x + (size_t)b * L_ * C_ + c;
        float pv = INFINITY;
        int   pi = 0x7fffffff;
        for (int k = 0; k < KTOP; ++k) {
            float bv = -INFINITY;
            int   bi = -1;
            for (int l = lane; l < L_; l += 64) {
                float vv = xc[(size_t)l * C_];
                if (lex_lt(vv, l, pv, pi) && lex_lt(bv, bi, vv, l)) {
                    bv = vv; bi = l;
                }
            }
#pragma unroll
            for (int off = 32; off; off >>= 1) {
                float ov = __shfl_xor(bv, off, 64);
                int   oi = __shfl_xor(bi, off, 64);
                if (lex_lt(bv, bi, ov, oi)) { bv = ov; bi = oi; }
            }
            pv = bv; pi = bi;
            if (lane == k) { keepv = bv; keepi = bi; }
        }
    }

    // rank this lane's winner by original index -> output row (temporal order)
    int pos = 0;
    for (int j = 0; j < KTOP; ++j) {
        int oi = __shfl(keepi, j, 64);
        pos += (oi < keepi);
    }
    out[((size_t)b * KTOP + pos) * C_ + c] = keepv;
}

extern "C" void kernel_launch(void* const* d_in, const int* in_sizes, int n_in,
                              void* d_out, int out_size, void* d_ws, size_t ws_size,
                              hipStream_t stream) {
    (void)in_sizes; (void)n_in; (void)out_size;
    const float* x  = (const float*)d_in[0];
    float*      out = (float*)d_out;

    int*   cnt       = (int*)d_ws;
    size_t cnt_bytes = (size_t)NCOL * sizeof(int);

    // size the candidate buffers from the workspace we actually have
    int cap = 0;
    if (ws_size > cnt_bytes) {
        size_t rem = ws_size - cnt_bytes;
        size_t c   = rem / ((size_t)NCOL * 8);  // 4B val + 4B idx per slot
        cap = (c > CAPMAX) ? CAPMAX : (int)c;
    }
    float* cval = (float*)((char*)d_ws + cnt_bytes);
    int*   cidx = (int*)((char*)d_ws + cnt_bytes + (size_t)NCOL * cap * sizeof(float));

    if (cap >= KTOP) {
        k_zero<<<NCOL / 256, 256, 0, stream>>>(cnt);
        dim3 g1(L_ / 256, B_);
        k_filter<<<g1, 256, 0, stream>>>(x, cnt, cval, cidx, cap);
    } else {
        cap = 0;  // workspace too small: k_select takes exact fallback for all
    }

    k_select<<<NCOL / 4, 256, 0, stream>>>(x, cnt, cval, cidx, out, cap);
}